// Round 9
// baseline (2127.591 us; speedup 1.0000x reference)
//
#include <hip/hip_runtime.h>
#include <math.h>

// BiometricLSTM: 2-layer LSTM, B=512, T=2048, I=3, H=64, fp32 in/out. Output = final h2 (B,64).
//
// R9: all-gates-in-one-lane restructure. R8's counters showed ~320 VALU
// instrs/wave-iter vs 136 in source (AGPR-operand tax on spilled weights) plus
// 2 barrier drains and an intra-iter LDS round-trip (gbuf). New layout removes
// the intra-iteration dependency: lane j of a wave owns ALL 4 gates of element j,
// so the state update happens in-register right after the dots.
//
// Wave roles (4 waves/block, 1 seq/block, 512 blocks = 2 blocks/CU):
//   role0: L0 elem j, step t=it   (it<TT):    4 dots Whh0.h1[t-1] + x + update -> h1[t]
//   role1: L1 ih gates i,f, step t=it-1 (1<=it<=TT): dots Wih1.h1[t] -> pA
//   role3: L1 ih gates g,o, same step        -> pA
//   role2: L1 hh + finish, step t=it-2 (it>=2): dots Whh1.h2[t-1] + pA gather +
//          update -> h2[t]; output at it==TT+1
// Lag-2 pipeline => every cross-wave dependency is >=1 iteration old =>
// ONE barrier per iteration with parity double-buffers (was 2 + gbuf phase).
// Roles permuted by (blockIdx>>8)&1 so co-resident blocks pair heavy+light
// waves on each SIMD. h kept f16 in LDS, dots via v_dot2_f32_f16 (f32 accum).

typedef _Float16 half2_t __attribute__((ext_vector_type(2)));

constexpr int TT = 2048;

__device__ __forceinline__ float fast_sigmoid(float x) {
    return 1.0f / (1.0f + __expf(-x));
}

// overflow-safe tanh: c can reach O(100s); exp(-2|x|) underflows harmlessly to 0 -> +/-1
__device__ __forceinline__ float fast_tanh(float x) {
    float ax = fabsf(x);
    float t  = __expf(-2.0f * ax);
    return copysignf((1.0f - t) / (1.0f + t), x);
}

// f32 += f16*f16 + f16*f16 (v_dot2_f32_f16); fallback keeps correctness if absent
__device__ __forceinline__ float dot2acc(half2_t a, half2_t b, float c) {
#if __has_builtin(__builtin_amdgcn_fdot2)
    return __builtin_amdgcn_fdot2(a, b, c, false);
#else
    c = fmaf((float)a[0], (float)b[0], c);
    return fmaf((float)a[1], (float)b[1], c);
#endif
}

__device__ __forceinline__ half2_t h2cast(float v) {
    return __builtin_bit_cast(half2_t, v);
}

__global__ __launch_bounds__(256) void lstm2_fused(
    const float* __restrict__ x,
    const float* __restrict__ Wih0, const float* __restrict__ Whh0,
    const float* __restrict__ bih0, const float* __restrict__ bhh0,
    const float* __restrict__ Wih1, const float* __restrict__ Whh1,
    const float* __restrict__ bih1, const float* __restrict__ bhh1,
    float* __restrict__ out)
{
    __shared__ __align__(16) float    xs4[TT * 4];       // 32 KB, stride-4 x
    __shared__ __align__(16) _Float16 h1buf[2][64];      // [stepParity][elem]
    __shared__ __align__(16) _Float16 h2buf[2][64];
    __shared__ __align__(16) float    pAbuf[2][4][64];   // ih partials [stepParity][gate][elem]

    const int tid  = threadIdx.x;
    const int lane = tid & 63;
    const int wid  = tid >> 6;
    // permute roles between the two co-resident blocks (blocks b and b+256 land
    // on the same CU under round-robin dispatch) so each SIMD gets heavy+light.
    const int role = (wid + ((blockIdx.x >> 8) & 1)) & 3;

    // ---- preload x: global (T,3) packed -> LDS stride 4 ----
    {
        const float* xg = x + (size_t)blockIdx.x * (TT * 3);
        for (int idx = tid; idx < TT * 3; idx += 256) {
            int t = idx / 3;              // magic-mul, no HW divide
            int c = idx - 3 * t;
            xs4[t * 4 + c] = xg[idx];
        }
    }
    // ---- zero h double-buffers ----
    if (tid < 128)        ((_Float16*)h1buf)[tid] = (_Float16)0.0f;
    else                  ((_Float16*)h2buf)[tid - 128] = (_Float16)0.0f;

    // ---- per-role weights (packed half2, registers) ----
    // role0: Whh0 rows {lane,64+lane,128+lane,192+lane} + Wih0 + bias0
    // role1: Wih1 rows {lane,64+lane}       role3: Wih1 rows {128+lane,192+lane}
    // role2: Whh1 rows {lane..192+lane} + bias1
    half2_t wreg[4][32];
    float wx[4][3];
    float bias[4];
    if (role == 0) {
        #pragma unroll
        for (int gi = 0; gi < 4; ++gi) {
            const int row = gi * 64 + lane;
            const float4* src = (const float4*)(Whh0 + row * 64);
            #pragma unroll
            for (int k = 0; k < 16; ++k) {
                float4 v = src[k];
                wreg[gi][2*k+0] = half2_t{(_Float16)v.x, (_Float16)v.y};
                wreg[gi][2*k+1] = half2_t{(_Float16)v.z, (_Float16)v.w};
            }
            wx[gi][0] = Wih0[row*3+0]; wx[gi][1] = Wih0[row*3+1]; wx[gi][2] = Wih0[row*3+2];
            bias[gi] = bih0[row] + bhh0[row];
        }
    } else if (role == 2) {
        #pragma unroll
        for (int gi = 0; gi < 4; ++gi) {
            const int row = gi * 64 + lane;
            const float4* src = (const float4*)(Whh1 + row * 64);
            #pragma unroll
            for (int k = 0; k < 16; ++k) {
                float4 v = src[k];
                wreg[gi][2*k+0] = half2_t{(_Float16)v.x, (_Float16)v.y};
                wreg[gi][2*k+1] = half2_t{(_Float16)v.z, (_Float16)v.w};
            }
            bias[gi] = bih1[row] + bhh1[row];
        }
    } else {
        const int gbase = (role == 1) ? 0 : 2;
        #pragma unroll
        for (int gi = 0; gi < 2; ++gi) {
            const int row = (gbase + gi) * 64 + lane;
            const float4* src = (const float4*)(Wih1 + row * 64);
            #pragma unroll
            for (int k = 0; k < 16; ++k) {
                float4 v = src[k];
                wreg[gi][2*k+0] = half2_t{(_Float16)v.x, (_Float16)v.y};
                wreg[gi][2*k+1] = half2_t{(_Float16)v.z, (_Float16)v.w};
            }
        }
    }

    float c_state = 0.0f;     // role0: c0[lane]; role2: c1[lane]

    __syncthreads();

    // lag-2 pipeline, TT+2 iterations, ONE barrier per iteration.
    for (int it = 0; it < TT + 2; ++it) {
        const int cur  = it & 1;
        const int prev = cur ^ 1;

        if (role == 0) {
            if (it < TT) {
                // L0 step it: gates = Whh0 . h1[it-1] + Wih0 . x[it] + bias
                const float4* hp = (const float4*)h1buf[prev];
                float a0=0.f,b0=0.f,a1=0.f,b1=0.f,a2=0.f,b2=0.f,a3=0.f,b3=0.f;
                #pragma unroll
                for (int q = 0; q < 8; ++q) {
                    float4 v = hp[q];
                    half2_t x0 = h2cast(v.x), x1 = h2cast(v.y);
                    half2_t x2 = h2cast(v.z), x3 = h2cast(v.w);
                    a0 = dot2acc(x0, wreg[0][4*q+0], a0); b0 = dot2acc(x1, wreg[0][4*q+1], b0);
                    a0 = dot2acc(x2, wreg[0][4*q+2], a0); b0 = dot2acc(x3, wreg[0][4*q+3], b0);
                    a1 = dot2acc(x0, wreg[1][4*q+0], a1); b1 = dot2acc(x1, wreg[1][4*q+1], b1);
                    a1 = dot2acc(x2, wreg[1][4*q+2], a1); b1 = dot2acc(x3, wreg[1][4*q+3], b1);
                    a2 = dot2acc(x0, wreg[2][4*q+0], a2); b2 = dot2acc(x1, wreg[2][4*q+1], b2);
                    a2 = dot2acc(x2, wreg[2][4*q+2], a2); b2 = dot2acc(x3, wreg[2][4*q+3], b2);
                    a3 = dot2acc(x0, wreg[3][4*q+0], a3); b3 = dot2acc(x1, wreg[3][4*q+1], b3);
                    a3 = dot2acc(x2, wreg[3][4*q+2], a3); b3 = dot2acc(x3, wreg[3][4*q+3], b3);
                }
                float4 xv = ((const float4*)xs4)[it];
                float gi_ = bias[0] + (a0+b0) + wx[0][0]*xv.x + wx[0][1]*xv.y + wx[0][2]*xv.z;
                float gf_ = bias[1] + (a1+b1) + wx[1][0]*xv.x + wx[1][1]*xv.y + wx[1][2]*xv.z;
                float gg_ = bias[2] + (a2+b2) + wx[2][0]*xv.x + wx[2][1]*xv.y + wx[2][2]*xv.z;
                float go_ = bias[3] + (a3+b3) + wx[3][0]*xv.x + wx[3][1]*xv.y + wx[3][2]*xv.z;
                float iv = fast_sigmoid(gi_), fv = fast_sigmoid(gf_);
                float gv = fast_tanh(gg_),    ov = fast_sigmoid(go_);
                c_state = fmaf(fv, c_state, iv * gv);
                h1buf[cur][lane] = (_Float16)(ov * fast_tanh(c_state));   // h1[it]
            }
        } else if (role == 2) {
            if (it >= 2) {
                // L1 step it-2: hh = Whh1 . h2[it-3]; + pA(step it-2) + bias
                const float4* hp = (const float4*)h2buf[prev];
                float a0=0.f,b0=0.f,a1=0.f,b1=0.f,a2=0.f,b2=0.f,a3=0.f,b3=0.f;
                #pragma unroll
                for (int q = 0; q < 8; ++q) {
                    float4 v = hp[q];
                    half2_t x0 = h2cast(v.x), x1 = h2cast(v.y);
                    half2_t x2 = h2cast(v.z), x3 = h2cast(v.w);
                    a0 = dot2acc(x0, wreg[0][4*q+0], a0); b0 = dot2acc(x1, wreg[0][4*q+1], b0);
                    a0 = dot2acc(x2, wreg[0][4*q+2], a0); b0 = dot2acc(x3, wreg[0][4*q+3], b0);
                    a1 = dot2acc(x0, wreg[1][4*q+0], a1); b1 = dot2acc(x1, wreg[1][4*q+1], b1);
                    a1 = dot2acc(x2, wreg[1][4*q+2], a1); b1 = dot2acc(x3, wreg[1][4*q+3], b1);
                    a2 = dot2acc(x0, wreg[2][4*q+0], a2); b2 = dot2acc(x1, wreg[2][4*q+1], b2);
                    a2 = dot2acc(x2, wreg[2][4*q+2], a2); b2 = dot2acc(x3, wreg[2][4*q+3], b2);
                    a3 = dot2acc(x0, wreg[3][4*q+0], a3); b3 = dot2acc(x1, wreg[3][4*q+1], b3);
                    a3 = dot2acc(x2, wreg[3][4*q+2], a3); b3 = dot2acc(x3, wreg[3][4*q+3], b3);
                }
                // pA for step it-2 lives at parity (it-2)&1 == cur
                float gi_ = bias[0] + (a0+b0) + pAbuf[cur][0][lane];
                float gf_ = bias[1] + (a1+b1) + pAbuf[cur][1][lane];
                float gg_ = bias[2] + (a2+b2) + pAbuf[cur][2][lane];
                float go_ = bias[3] + (a3+b3) + pAbuf[cur][3][lane];
                float iv = fast_sigmoid(gi_), fv = fast_sigmoid(gf_);
                float gv = fast_tanh(gg_),    ov = fast_sigmoid(go_);
                c_state = fmaf(fv, c_state, iv * gv);
                float hv = ov * fast_tanh(c_state);
                h2buf[cur][lane] = (_Float16)hv;                          // h2[it-2]
                if (it == TT + 1)
                    out[(size_t)blockIdx.x * 64 + lane] = hv;
            }
        } else {
            if (it >= 1 && it <= TT) {
                // L1 ih half, step it-1: dots Wih1 . h1[it-1]
                const float4* hp = (const float4*)h1buf[prev];
                float a0=0.f,b0=0.f,a1=0.f,b1=0.f;
                #pragma unroll
                for (int q = 0; q < 8; ++q) {
                    float4 v = hp[q];
                    half2_t x0 = h2cast(v.x), x1 = h2cast(v.y);
                    half2_t x2 = h2cast(v.z), x3 = h2cast(v.w);
                    a0 = dot2acc(x0, wreg[0][4*q+0], a0); b0 = dot2acc(x1, wreg[0][4*q+1], b0);
                    a0 = dot2acc(x2, wreg[0][4*q+2], a0); b0 = dot2acc(x3, wreg[0][4*q+3], b0);
                    a1 = dot2acc(x0, wreg[1][4*q+0], a1); b1 = dot2acc(x1, wreg[1][4*q+1], b1);
                    a1 = dot2acc(x2, wreg[1][4*q+2], a1); b1 = dot2acc(x3, wreg[1][4*q+3], b1);
                }
                const int gbase = (role == 1) ? 0 : 2;
                // step it-1 parity == prev
                pAbuf[prev][gbase + 0][lane] = a0 + b0;
                pAbuf[prev][gbase + 1][lane] = a1 + b1;
            }
        }
        __syncthreads();
    }
}

extern "C" void kernel_launch(void* const* d_in, const int* in_sizes, int n_in,
                              void* d_out, int out_size, void* d_ws, size_t ws_size,
                              hipStream_t stream) {
    const float* x    = (const float*)d_in[0];
    const float* Wih0 = (const float*)d_in[1];
    const float* Whh0 = (const float*)d_in[2];
    const float* bih0 = (const float*)d_in[3];
    const float* bhh0 = (const float*)d_in[4];
    const float* Wih1 = (const float*)d_in[5];
    const float* Whh1 = (const float*)d_in[6];
    const float* bih1 = (const float*)d_in[7];
    const float* bhh1 = (const float*)d_in[8];
    float* out = (float*)d_out;

    // 512 sequences, 1 per block -> 512 blocks = 2 blocks/CU; 256 threads (4 waves).
    lstm2_fused<<<512, 256, 0, stream>>>(x, Wih0, Whh0, bih0, bhh0,
                                         Wih1, Whh1, bih1, bhh1, out);
}